// Round 5
// baseline (254.732 us; speedup 1.0000x reference)
//
#include <hip/hip_runtime.h>
#include <math.h>

#define B_ 16
#define C_ 64
#define H_ 256
#define W_ 256
#define HW_ 65536

typedef __attribute__((ext_vector_type(8))) unsigned short us8v;
typedef __attribute__((ext_vector_type(4))) float f4v;

__device__ __forceinline__ float b2f(unsigned short h) {
    return __uint_as_float(((unsigned int)h) << 16);
}
__device__ __forceinline__ unsigned short f2b(float f) {
    unsigned int u = __float_as_uint(f);
    u += 0x7FFFu + ((u >> 16) & 1u);   // round-to-nearest-even
    return (unsigned short)(u >> 16);
}

__device__ __forceinline__ float waveSum(float v) {
#pragma unroll
    for (int o = 32; o > 0; o >>= 1) v += __shfl_down(v, o, 64);
    return v;
}
__device__ __forceinline__ float waveMax(float v) {
#pragma unroll
    for (int o = 32; o > 0; o >>= 1) v = fmaxf(v, __shfl_down(v, o, 64));
    return v;
}

// K1: per-(b,c) spatial sum & max of weight; transcode weight -> bf16 copy.
// fp32 weight is read-once -> nontemporal loads keep wq L3-resident.
__global__ __launch_bounds__(512) void reduce_weight_q(const float* __restrict__ w,
                              us8v* __restrict__ wq,
                              float* __restrict__ wsum, float* __restrict__ wmax) {
    int bc = blockIdx.x;
    const f4v* p = (const f4v*)(w + (size_t)bc * HW_);
    us8v* q = wq + (size_t)bc * (HW_ / 8);
    float s = 0.f, m = -INFINITY;
#pragma unroll 4
    for (int i = threadIdx.x; i < HW_ / 8; i += 512) {
        f4v a = __builtin_nontemporal_load(p + 2 * i);
        f4v c = __builtin_nontemporal_load(p + 2 * i + 1);
        s += (a.x + a.y) + (a.z + a.w) + (c.x + c.y) + (c.z + c.w);
        m = fmaxf(m, fmaxf(fmaxf(a.x, a.y), fmaxf(a.z, a.w)));
        m = fmaxf(m, fmaxf(fmaxf(c.x, c.y), fmaxf(c.z, c.w)));
        us8v o;
        o[0] = f2b(a.x); o[1] = f2b(a.y); o[2] = f2b(a.z); o[3] = f2b(a.w);
        o[4] = f2b(c.x); o[5] = f2b(c.y); o[6] = f2b(c.z); o[7] = f2b(c.w);
        q[i] = o;
    }
    __shared__ float ts[8], tm[8];
    int wid = threadIdx.x >> 6, lane = threadIdx.x & 63;
    s = waveSum(s);
    m = waveMax(m);
    if (lane == 0) { ts[wid] = s; tm[wid] = m; }
    __syncthreads();
    if (threadIdx.x == 0) {
        float a = 0.f, qm = -INFINITY;
#pragma unroll
        for (int j = 0; j < 8; ++j) { a += ts[j]; qm = fmaxf(qm, tm[j]); }
        wsum[bc] = a;
        wmax[bc] = qm;
    }
}

// K2: channel-attention MLP (redundant per block) + per-pixel channel mean/max
// of ca*weight (bf16 source). grid=(32,16), 256 thr, 8 pixels/thread.
__global__ __launch_bounds__(256) void ca_spatial(const us8v* __restrict__ wq,
                           const float* __restrict__ wsum, const float* __restrict__ wmax,
                           const float* __restrict__ fc1, const float* __restrict__ fc2,
                           float* __restrict__ spm, float* __restrict__ spx,
                           float* __restrict__ ca_out) {
    int b = blockIdx.y;
    int t = threadIdx.x;
    __shared__ float hid[16];
    __shared__ float cas[64];
    if (t < 16) {
        int j = t & 7;
        const float* src = (t < 8) ? wsum : wmax;
        float scale = (t < 8) ? (1.f / (float)HW_) : 1.f;
        float s = 0.f;
#pragma unroll 8
        for (int c = 0; c < 64; ++c) s += fc1[j * 64 + c] * (src[b * 64 + c] * scale);
        hid[t] = fmaxf(s, 0.f);
    }
    __syncthreads();
    if (t < 64) {
        float o = 0.f;
#pragma unroll
        for (int j = 0; j < 8; ++j) o += (hid[j] + hid[8 + j]) * fc2[t * 8 + j];
        float c = 1.f / (1.f + expf(-o));
        cas[t] = c;
        if (blockIdx.x == 0) ca_out[b * 64 + t] = c;
    }
    __syncthreads();

    int pix8 = blockIdx.x * 256 + t;   // us8v (8-pixel) index within plane
    const us8v* base = wq + (size_t)b * 64 * (HW_ / 8);
    float s[8], mm[8];
#pragma unroll
    for (int j = 0; j < 8; ++j) { s[j] = 0.f; mm[j] = -INFINITY; }
#pragma unroll 8
    for (int c = 0; c < 64; ++c) {
        us8v u = base[(size_t)c * (HW_ / 8) + pix8];
        float a = cas[c];
#pragma unroll
        for (int j = 0; j < 8; ++j) {
            float v = a * b2f(u[j]);
            s[j] += v;
            mm[j] = fmaxf(mm[j], v);
        }
    }
    const float inv = 1.f / 64.f;
    float4* pm = (float4*)spm + (size_t)b * (HW_ / 4) + pix8 * 2;
    float4* px = (float4*)spx + (size_t)b * (HW_ / 4) + pix8 * 2;
    pm[0] = make_float4(s[0] * inv, s[1] * inv, s[2] * inv, s[3] * inv);
    pm[1] = make_float4(s[4] * inv, s[5] * inv, s[6] * inv, s[7] * inv);
    px[0] = make_float4(mm[0], mm[1], mm[2], mm[3]);
    px[1] = make_float4(mm[4], mm[5], mm[6], mm[7]);
}

// K3: 7x7 conv over [mean,max] -> sigmoid. grid=(256,16), 256 thr (one row).
__global__ void sa_conv(const float* __restrict__ spm, const float* __restrict__ spx,
                        const float* __restrict__ sw, float* __restrict__ sa) {
    int b = blockIdx.y, y = blockIdx.x, x = threadIdx.x;
    const float* in0 = spm + (size_t)b * HW_;
    const float* in1 = spx + (size_t)b * HW_;
    float acc = 0.f;
#pragma unroll
    for (int ky = 0; ky < 7; ++ky) {
        int yy = y + ky - 3;
        if (yy < 0 || yy >= H_) continue;
        const float* r0 = in0 + yy * W_;
        const float* r1 = in1 + yy * W_;
#pragma unroll
        for (int kx = 0; kx < 7; ++kx) {
            int xx = x + kx - 3;
            if (xx < 0 || xx >= W_) continue;
            acc += r0[xx] * sw[ky * 7 + kx] + r1[xx] * sw[49 + ky * 7 + kx];
        }
    }
    sa[(size_t)b * HW_ + y * W_ + x] = 1.f / (1.f + expf(-acc));
}

// K4: sval[b,c] = mean_hw(sa * weight) from bf16 weight (last use -> nt loads).
// grid=1024 (XCD-chunked), 512 thr.
__global__ __launch_bounds__(512) void weighted_reduce(const us8v* __restrict__ wq,
                                const float* __restrict__ sa,
                                float* __restrict__ sval) {
    int d = blockIdx.x;
    int bc = ((d & 7) << 7) + (d >> 3);   // XCD-chunked: each XCD owns 2 images
    int b = bc >> 6;
    const us8v* wp = wq + (size_t)bc * (HW_ / 8);
    const float4* sp = (const float4*)(sa + (size_t)b * HW_);
    float s = 0.f;
#pragma unroll 4
    for (int i = threadIdx.x; i < HW_ / 8; i += 512) {
        us8v u = __builtin_nontemporal_load(wp + i);
        float4 q0 = sp[2 * i], q1 = sp[2 * i + 1];
        s += b2f(u[0]) * q0.x + b2f(u[1]) * q0.y + b2f(u[2]) * q0.z + b2f(u[3]) * q0.w
           + b2f(u[4]) * q1.x + b2f(u[5]) * q1.y + b2f(u[6]) * q1.z + b2f(u[7]) * q1.w;
    }
    __shared__ float ts[8];
    int wid = threadIdx.x >> 6, lane = threadIdx.x & 63;
    s = waveSum(s);
    if (lane == 0) ts[wid] = s;
    __syncthreads();
    if (threadIdx.x == 0) {
        float a = 0.f;
#pragma unroll
        for (int j = 0; j < 8; ++j) a += ts[j];
        sval[bc] = a * (1.f / (float)HW_);
    }
}

// K5: build per-sample kernel (redundant per block) + dynamic 3x3x64 conv.
// float4 loads + wave-shuffle column halo. grid=1024 (16 b x 64 tiles of 4 rows,
// XCD-chunked), 256 thr: thread = (col4 = t&63, row r = t>>6).
__global__ __launch_bounds__(256) void final_conv(const float* __restrict__ x1,
                           const float* __restrict__ ca, const float* __restrict__ sval,
                           const float* __restrict__ pk1w, const float* __restrict__ pk1b,
                           const float* __restrict__ pk2w, const float* __restrict__ pk2b,
                           float* __restrict__ out) {
    int d = blockIdx.x;
    int gid = ((d & 7) << 7) + (d >> 3);  // XCD-chunked: each XCD owns 2 images
    int b = gid >> 6;
    int y0 = (gid & 63) * 4;
    int t = threadIdx.x;
    __shared__ float wg[64];
    __shared__ float kern[64][9];
    if (t < 64) wg[t] = ca[b * 64 + t] * sval[b * 64 + t];
    __syncthreads();
    if (t < 64) {
        float p = pk1b[t];
#pragma unroll 8
        for (int c = 0; c < 64; ++c) p += pk1w[t * 64 + c] * wg[c];
#pragma unroll
        for (int j = 0; j < 9; ++j) kern[t][j] = p * pk2w[t * 9 + j] + pk2b[t * 9 + j];
    }
    __syncthreads();

    int col4 = t & 63;          // float4 column
    int y = y0 + (t >> 6);      // this thread's output row
    float4 acc = make_float4(0.f, 0.f, 0.f, 0.f);

    for (int ic = 0; ic < 64; ++ic) {
        const float4* p4 = (const float4*)(x1 + ((size_t)(b * 64 + ic) << 16));
#pragma unroll
        for (int j = -1; j <= 1; ++j) {
            int yy = y + j;
            float4 v = make_float4(0.f, 0.f, 0.f, 0.f);
            if (yy >= 0 && yy < H_) v = p4[yy * (W_ / 4) + col4];
            float L = __shfl_up(v.w, 1);
            float R = __shfl_down(v.x, 1);
            if (col4 == 0) L = 0.f;
            if (col4 == 63) R = 0.f;
            float ka = kern[ic][(j + 1) * 3 + 0];
            float kb = kern[ic][(j + 1) * 3 + 1];
            float kc = kern[ic][(j + 1) * 3 + 2];
            acc.x += L   * ka + v.x * kb + v.y * kc;
            acc.y += v.x * ka + v.y * kb + v.z * kc;
            acc.z += v.y * ka + v.z * kb + v.w * kc;
            acc.w += v.z * ka + v.w * kb + R   * kc;
        }
    }
    ((float4*)(out + (size_t)b * HW_ + (size_t)y * W_))[col4] = acc;
}

extern "C" void kernel_launch(void* const* d_in, const int* in_sizes, int n_in,
                              void* d_out, int out_size, void* d_ws, size_t ws_size,
                              hipStream_t stream) {
    const float* x1     = (const float*)d_in[0];
    const float* weight = (const float*)d_in[1];
    const float* fc1    = (const float*)d_in[2];
    const float* fc2    = (const float*)d_in[3];
    const float* saw    = (const float*)d_in[4];
    const float* pk1w   = (const float*)d_in[5];
    const float* pk1b   = (const float*)d_in[6];
    const float* pk2w   = (const float*)d_in[7];
    const float* pk2b   = (const float*)d_in[8];
    float* out = (float*)d_out;

    float* ws   = (float*)d_ws;
    float* wsum = ws;                         // 1024
    float* wmax = ws + 1024;                  // 1024
    float* ca   = ws + 2048;                  // 1024
    float* sval = ws + 3072;                  // 1024
    float* spm  = ws + 16384;                 // 1048576
    float* spx  = spm + (size_t)B_ * HW_;     // 1048576
    float* sa   = spx + (size_t)B_ * HW_;     // 1048576
    us8v*  wq   = (us8v*)(ws + 16384 + 3u * 1048576u);  // 16M bf16 = 32 MB

    reduce_weight_q<<<dim3(B_ * C_), 512, 0, stream>>>(weight, wq, wsum, wmax);
    ca_spatial<<<dim3(32, B_), 256, 0, stream>>>(wq, wsum, wmax, fc1, fc2, spm, spx, ca);
    sa_conv<<<dim3(H_, B_), 256, 0, stream>>>(spm, spx, saw, sa);
    weighted_reduce<<<dim3(B_ * C_), 512, 0, stream>>>(wq, sa, sval);
    final_conv<<<dim3(B_ * C_), 256, 0, stream>>>(x1, ca, sval, pk1w, pk1b, pk2w, pk2b, out);
}

// Round 6
// 232.034 us; speedup vs baseline: 1.0978x; 1.0978x over previous
//
#include <hip/hip_runtime.h>
#include <math.h>

#define B_ 16
#define C_ 64
#define H_ 256
#define W_ 256
#define HW_ 65536

typedef __attribute__((ext_vector_type(8))) unsigned short us8v;
typedef __attribute__((ext_vector_type(4))) float f4v;

__device__ __forceinline__ float b2f(unsigned short h) {
    return __uint_as_float(((unsigned int)h) << 16);
}
__device__ __forceinline__ unsigned short f2b(float f) {
    unsigned int u = __float_as_uint(f);
    u += 0x7FFFu + ((u >> 16) & 1u);   // round-to-nearest-even
    return (unsigned short)(u >> 16);
}

__device__ __forceinline__ float waveSum(float v) {
#pragma unroll
    for (int o = 32; o > 0; o >>= 1) v += __shfl_down(v, o, 64);
    return v;
}
__device__ __forceinline__ float waveMax(float v) {
#pragma unroll
    for (int o = 32; o > 0; o >>= 1) v = fmaxf(v, __shfl_down(v, o, 64));
    return v;
}

// K1: per-(b,c) spatial sum & max of weight; transcode weight -> bf16 copy.
// fp32 weight is read-once: NT loads so the 268MB stream doesn't evict wq
// (134MB) from Infinity Cache. wq writes allocate normally.
__global__ __launch_bounds__(512) void reduce_weight_q(const float* __restrict__ w,
                              us8v* __restrict__ wq,
                              float* __restrict__ wsum, float* __restrict__ wmax) {
    int bc = blockIdx.x;
    const f4v* p = (const f4v*)(w + (size_t)bc * HW_);
    us8v* q = wq + (size_t)bc * (HW_ / 8);
    float s = 0.f, m = -INFINITY;
#pragma unroll 4
    for (int i = threadIdx.x; i < HW_ / 8; i += 512) {
        f4v a = __builtin_nontemporal_load(p + 2 * i);
        f4v c = __builtin_nontemporal_load(p + 2 * i + 1);
        s += (a.x + a.y) + (a.z + a.w) + (c.x + c.y) + (c.z + c.w);
        m = fmaxf(m, fmaxf(fmaxf(a.x, a.y), fmaxf(a.z, a.w)));
        m = fmaxf(m, fmaxf(fmaxf(c.x, c.y), fmaxf(c.z, c.w)));
        us8v o;
        o[0] = f2b(a.x); o[1] = f2b(a.y); o[2] = f2b(a.z); o[3] = f2b(a.w);
        o[4] = f2b(c.x); o[5] = f2b(c.y); o[6] = f2b(c.z); o[7] = f2b(c.w);
        q[i] = o;
    }
    __shared__ float ts[8], tm[8];
    int wid = threadIdx.x >> 6, lane = threadIdx.x & 63;
    s = waveSum(s);
    m = waveMax(m);
    if (lane == 0) { ts[wid] = s; tm[wid] = m; }
    __syncthreads();
    if (threadIdx.x == 0) {
        float a = 0.f, qm = -INFINITY;
#pragma unroll
        for (int j = 0; j < 8; ++j) { a += ts[j]; qm = fmaxf(qm, tm[j]); }
        wsum[bc] = a;
        wmax[bc] = qm;
    }
}

// K2: channel-attention MLP (redundant per block) + per-pixel channel mean/max
// of ca*weight (bf16 source). grid=(32,16), 256 thr, 8 pixels/thread.
__global__ __launch_bounds__(256) void ca_spatial(const us8v* __restrict__ wq,
                           const float* __restrict__ wsum, const float* __restrict__ wmax,
                           const float* __restrict__ fc1, const float* __restrict__ fc2,
                           float* __restrict__ spm, float* __restrict__ spx,
                           float* __restrict__ ca_out) {
    int b = blockIdx.y;
    int t = threadIdx.x;
    __shared__ float hid[16];
    __shared__ float cas[64];
    if (t < 16) {
        int j = t & 7;
        const float* src = (t < 8) ? wsum : wmax;
        float scale = (t < 8) ? (1.f / (float)HW_) : 1.f;
        float s = 0.f;
#pragma unroll 8
        for (int c = 0; c < 64; ++c) s += fc1[j * 64 + c] * (src[b * 64 + c] * scale);
        hid[t] = fmaxf(s, 0.f);
    }
    __syncthreads();
    if (t < 64) {
        float o = 0.f;
#pragma unroll
        for (int j = 0; j < 8; ++j) o += (hid[j] + hid[8 + j]) * fc2[t * 8 + j];
        float c = 1.f / (1.f + expf(-o));
        cas[t] = c;
        if (blockIdx.x == 0) ca_out[b * 64 + t] = c;
    }
    __syncthreads();

    int pix8 = blockIdx.x * 256 + t;   // us8v (8-pixel) index within plane
    const us8v* base = wq + (size_t)b * 64 * (HW_ / 8);
    float s[8], mm[8];
#pragma unroll
    for (int j = 0; j < 8; ++j) { s[j] = 0.f; mm[j] = -INFINITY; }
#pragma unroll 8
    for (int c = 0; c < 64; ++c) {
        us8v u = base[(size_t)c * (HW_ / 8) + pix8];
        float a = cas[c];
#pragma unroll
        for (int j = 0; j < 8; ++j) {
            float v = a * b2f(u[j]);
            s[j] += v;
            mm[j] = fmaxf(mm[j], v);
        }
    }
    const float inv = 1.f / 64.f;
    float4* pm = (float4*)spm + (size_t)b * (HW_ / 4) + pix8 * 2;
    float4* px = (float4*)spx + (size_t)b * (HW_ / 4) + pix8 * 2;
    pm[0] = make_float4(s[0] * inv, s[1] * inv, s[2] * inv, s[3] * inv);
    pm[1] = make_float4(s[4] * inv, s[5] * inv, s[6] * inv, s[7] * inv);
    px[0] = make_float4(mm[0], mm[1], mm[2], mm[3]);
    px[1] = make_float4(mm[4], mm[5], mm[6], mm[7]);
}

// K3: 7x7 conv over [mean,max] -> sigmoid. grid=(256,16), 256 thr (one row).
__global__ void sa_conv(const float* __restrict__ spm, const float* __restrict__ spx,
                        const float* __restrict__ sw, float* __restrict__ sa) {
    int b = blockIdx.y, y = blockIdx.x, x = threadIdx.x;
    const float* in0 = spm + (size_t)b * HW_;
    const float* in1 = spx + (size_t)b * HW_;
    float acc = 0.f;
#pragma unroll
    for (int ky = 0; ky < 7; ++ky) {
        int yy = y + ky - 3;
        if (yy < 0 || yy >= H_) continue;
        const float* r0 = in0 + yy * W_;
        const float* r1 = in1 + yy * W_;
#pragma unroll
        for (int kx = 0; kx < 7; ++kx) {
            int xx = x + kx - 3;
            if (xx < 0 || xx >= W_) continue;
            acc += r0[xx] * sw[ky * 7 + kx] + r1[xx] * sw[49 + ky * 7 + kx];
        }
    }
    sa[(size_t)b * HW_ + y * W_ + x] = 1.f / (1.f + expf(-acc));
}

// K4: sval[b,c] = mean_hw(sa * weight) from bf16 weight (normal loads: wq
// should be L3-resident). grid=1024 (XCD-chunked), 512 thr.
__global__ __launch_bounds__(512) void weighted_reduce(const us8v* __restrict__ wq,
                                const float* __restrict__ sa,
                                float* __restrict__ sval) {
    int d = blockIdx.x;
    int bc = ((d & 7) << 7) + (d >> 3);   // XCD-chunked: each XCD owns 2 images
    int b = bc >> 6;
    const us8v* wp = wq + (size_t)bc * (HW_ / 8);
    const float4* sp = (const float4*)(sa + (size_t)b * HW_);
    float s = 0.f;
#pragma unroll 4
    for (int i = threadIdx.x; i < HW_ / 8; i += 512) {
        us8v u = wp[i];
        float4 q0 = sp[2 * i], q1 = sp[2 * i + 1];
        s += b2f(u[0]) * q0.x + b2f(u[1]) * q0.y + b2f(u[2]) * q0.z + b2f(u[3]) * q0.w
           + b2f(u[4]) * q1.x + b2f(u[5]) * q1.y + b2f(u[6]) * q1.z + b2f(u[7]) * q1.w;
    }
    __shared__ float ts[8];
    int wid = threadIdx.x >> 6, lane = threadIdx.x & 63;
    s = waveSum(s);
    if (lane == 0) ts[wid] = s;
    __syncthreads();
    if (threadIdx.x == 0) {
        float a = 0.f;
#pragma unroll
        for (int j = 0; j < 8; ++j) a += ts[j];
        sval[bc] = a * (1.f / (float)HW_);
    }
}

// K5: build per-sample kernel (redundant per block) + dynamic 3x3x64 conv.
// grid=1024 (16 b x 64 tiles of 4 rows, XCD-chunked), 256 thr. (round-4 form)
__global__ __launch_bounds__(256) void final_conv(const float* __restrict__ x1,
                           const float* __restrict__ ca, const float* __restrict__ sval,
                           const float* __restrict__ pk1w, const float* __restrict__ pk1b,
                           const float* __restrict__ pk2w, const float* __restrict__ pk2b,
                           float* __restrict__ out) {
    int d = blockIdx.x;
    int gid = ((d & 7) << 7) + (d >> 3);  // XCD-chunked: each XCD owns 2 images
    int b = gid >> 6;
    int y0 = (gid & 63) * 4;
    int t = threadIdx.x;
    __shared__ float wg[64];
    __shared__ float kern[64][9];
    if (t < 64) wg[t] = ca[b * 64 + t] * sval[b * 64 + t];
    __syncthreads();
    if (t < 64) {
        float p = pk1b[t];
#pragma unroll 8
        for (int c = 0; c < 64; ++c) p += pk1w[t * 64 + c] * wg[c];
#pragma unroll
        for (int j = 0; j < 9; ++j) kern[t][j] = p * pk2w[t * 9 + j] + pk2b[t * 9 + j];
    }
    __syncthreads();

    int x = t;
    float acc[4] = {0.f, 0.f, 0.f, 0.f};

    for (int ic = 0; ic < 64; ++ic) {
        const float* plane = x1 + ((size_t)(b * 64 + ic) << 16);
        float k0 = kern[ic][0], k1 = kern[ic][1], k2 = kern[ic][2];
        float k3 = kern[ic][3], k4 = kern[ic][4], k5 = kern[ic][5];
        float k6 = kern[ic][6], k7 = kern[ic][7], k8 = kern[ic][8];
#pragma unroll
        for (int j = -1; j <= 4; ++j) {
            int yy = y0 + j;
            float m = 0.f, z = 0.f, p = 0.f;
            if (yy >= 0 && yy < H_) {
                const float* row = plane + yy * W_;
                z = row[x];
                m = (x > 0) ? row[x - 1] : 0.f;
                p = (x < W_ - 1) ? row[x + 1] : 0.f;
            }
            if (j <= 2) acc[j + 1] += m * k0 + z * k1 + p * k2;
            if (j >= 0 && j <= 3) acc[j] += m * k3 + z * k4 + p * k5;
            if (j >= 1) acc[j - 1] += m * k6 + z * k7 + p * k8;
        }
    }
#pragma unroll
    for (int r = 0; r < 4; ++r)
        out[(size_t)b * HW_ + (size_t)(y0 + r) * W_ + x] = acc[r];
}

extern "C" void kernel_launch(void* const* d_in, const int* in_sizes, int n_in,
                              void* d_out, int out_size, void* d_ws, size_t ws_size,
                              hipStream_t stream) {
    const float* x1     = (const float*)d_in[0];
    const float* weight = (const float*)d_in[1];
    const float* fc1    = (const float*)d_in[2];
    const float* fc2    = (const float*)d_in[3];
    const float* saw    = (const float*)d_in[4];
    const float* pk1w   = (const float*)d_in[5];
    const float* pk1b   = (const float*)d_in[6];
    const float* pk2w   = (const float*)d_in[7];
    const float* pk2b   = (const float*)d_in[8];
    float* out = (float*)d_out;

    float* ws   = (float*)d_ws;
    float* wsum = ws;                         // 1024
    float* wmax = ws + 1024;                  // 1024
    float* ca   = ws + 2048;                  // 1024
    float* sval = ws + 3072;                  // 1024
    float* spm  = ws + 16384;                 // 1048576
    float* spx  = spm + (size_t)B_ * HW_;     // 1048576
    float* sa   = spx + (size_t)B_ * HW_;     // 1048576
    us8v*  wq   = (us8v*)(ws + 16384 + 3u * 1048576u);  // 16M bf16 = 32 MB

    reduce_weight_q<<<dim3(B_ * C_), 512, 0, stream>>>(weight, wq, wsum, wmax);
    ca_spatial<<<dim3(32, B_), 256, 0, stream>>>(wq, wsum, wmax, fc1, fc2, spm, spx, ca);
    sa_conv<<<dim3(H_, B_), 256, 0, stream>>>(spm, spx, saw, sa);
    weighted_reduce<<<dim3(B_ * C_), 512, 0, stream>>>(wq, sa, sval);
    final_conv<<<dim3(B_ * C_), 256, 0, stream>>>(x1, ca, sval, pk1w, pk1b, pk2w, pk2b, out);
}

// Round 7
// 201.349 us; speedup vs baseline: 1.2651x; 1.1524x over previous
//
#include <hip/hip_runtime.h>
#include <math.h>

#define B_ 16
#define C_ 64
#define H_ 256
#define W_ 256
#define HW_ 65536

typedef __attribute__((ext_vector_type(4))) float f4v;
typedef __attribute__((ext_vector_type(2))) float f2v;
typedef __attribute__((ext_vector_type(2))) unsigned int u2v;

__device__ __forceinline__ float waveSum(float v) {
#pragma unroll
    for (int o = 32; o > 0; o >>= 1) v += __shfl_down(v, o, 64);
    return v;
}
__device__ __forceinline__ float waveMax(float v) {
#pragma unroll
    for (int o = 32; o > 0; o >>= 1) v = fmaxf(v, __shfl_down(v, o, 64));
    return v;
}

// K1: per-(b,c) spatial sum & max of weight; transcode weight -> fp8 e4m3 copy
// (HW cvt). fp32 weight is read-once -> NT loads. grid=1024 planes, 512 thr.
__global__ __launch_bounds__(512) void reduce_weight_q(const float* __restrict__ w,
                              u2v* __restrict__ wq,
                              float* __restrict__ wsum, float* __restrict__ wmax) {
    int bc = blockIdx.x;
    const f4v* p = (const f4v*)(w + (size_t)bc * HW_);
    u2v* q = wq + (size_t)bc * (HW_ / 8);
    float s = 0.f, m = -INFINITY;
#pragma unroll 4
    for (int i = threadIdx.x; i < HW_ / 8; i += 512) {
        f4v a = __builtin_nontemporal_load(p + 2 * i);
        f4v c = __builtin_nontemporal_load(p + 2 * i + 1);
        s += (a.x + a.y) + (a.z + a.w) + (c.x + c.y) + (c.z + c.w);
        m = fmaxf(m, fmaxf(fmaxf(a.x, a.y), fmaxf(a.z, a.w)));
        m = fmaxf(m, fmaxf(fmaxf(c.x, c.y), fmaxf(c.z, c.w)));
        unsigned int lo = __builtin_amdgcn_cvt_pk_fp8_f32(a.x, a.y, 0u, false);
        lo = __builtin_amdgcn_cvt_pk_fp8_f32(a.z, a.w, lo, true);
        unsigned int hi = __builtin_amdgcn_cvt_pk_fp8_f32(c.x, c.y, 0u, false);
        hi = __builtin_amdgcn_cvt_pk_fp8_f32(c.z, c.w, hi, true);
        u2v o; o.x = lo; o.y = hi;
        q[i] = o;
    }
    __shared__ float ts[8], tm[8];
    int wid = threadIdx.x >> 6, lane = threadIdx.x & 63;
    s = waveSum(s);
    m = waveMax(m);
    if (lane == 0) { ts[wid] = s; tm[wid] = m; }
    __syncthreads();
    if (threadIdx.x == 0) {
        float a = 0.f, qm = -INFINITY;
#pragma unroll
        for (int j = 0; j < 8; ++j) { a += ts[j]; qm = fmaxf(qm, tm[j]); }
        wsum[bc] = a;
        wmax[bc] = qm;
    }
}

// K2: channel-attention MLP (redundant per block) + per-pixel channel mean/max
// of ca*weight (fp8 source). grid=(32,16), 256 thr, 8 pixels/thread.
__global__ __launch_bounds__(256) void ca_spatial(const u2v* __restrict__ wq,
                           const float* __restrict__ wsum, const float* __restrict__ wmax,
                           const float* __restrict__ fc1, const float* __restrict__ fc2,
                           float* __restrict__ spm, float* __restrict__ spx,
                           float* __restrict__ ca_out) {
    int b = blockIdx.y;
    int t = threadIdx.x;
    __shared__ float hid[16];
    __shared__ float cas[64];
    if (t < 16) {
        int j = t & 7;
        const float* src = (t < 8) ? wsum : wmax;
        float scale = (t < 8) ? (1.f / (float)HW_) : 1.f;
        float s = 0.f;
#pragma unroll 8
        for (int c = 0; c < 64; ++c) s += fc1[j * 64 + c] * (src[b * 64 + c] * scale);
        hid[t] = fmaxf(s, 0.f);
    }
    __syncthreads();
    if (t < 64) {
        float o = 0.f;
#pragma unroll
        for (int j = 0; j < 8; ++j) o += (hid[j] + hid[8 + j]) * fc2[t * 8 + j];
        float c = 1.f / (1.f + expf(-o));
        cas[t] = c;
        if (blockIdx.x == 0) ca_out[b * 64 + t] = c;
    }
    __syncthreads();

    int pix8 = blockIdx.x * 256 + t;   // 8-pixel index within plane
    const u2v* base = wq + (size_t)b * 64 * (HW_ / 8);
    float s[8], mm[8];
#pragma unroll
    for (int j = 0; j < 8; ++j) { s[j] = 0.f; mm[j] = -INFINITY; }
#pragma unroll 8
    for (int c = 0; c < 64; ++c) {
        u2v u = base[(size_t)c * (HW_ / 8) + pix8];
        float a = cas[c];
        f2v p01 = __builtin_amdgcn_cvt_pk_f32_fp8(u.x, false);
        f2v p23 = __builtin_amdgcn_cvt_pk_f32_fp8(u.x, true);
        f2v p45 = __builtin_amdgcn_cvt_pk_f32_fp8(u.y, false);
        f2v p67 = __builtin_amdgcn_cvt_pk_f32_fp8(u.y, true);
        float v0 = a * p01.x, v1 = a * p01.y, v2 = a * p23.x, v3 = a * p23.y;
        float v4 = a * p45.x, v5 = a * p45.y, v6 = a * p67.x, v7 = a * p67.y;
        s[0] += v0; s[1] += v1; s[2] += v2; s[3] += v3;
        s[4] += v4; s[5] += v5; s[6] += v6; s[7] += v7;
        mm[0] = fmaxf(mm[0], v0); mm[1] = fmaxf(mm[1], v1);
        mm[2] = fmaxf(mm[2], v2); mm[3] = fmaxf(mm[3], v3);
        mm[4] = fmaxf(mm[4], v4); mm[5] = fmaxf(mm[5], v5);
        mm[6] = fmaxf(mm[6], v6); mm[7] = fmaxf(mm[7], v7);
    }
    const float inv = 1.f / 64.f;
    float4* pm = (float4*)spm + (size_t)b * (HW_ / 4) + pix8 * 2;
    float4* px = (float4*)spx + (size_t)b * (HW_ / 4) + pix8 * 2;
    pm[0] = make_float4(s[0] * inv, s[1] * inv, s[2] * inv, s[3] * inv);
    pm[1] = make_float4(s[4] * inv, s[5] * inv, s[6] * inv, s[7] * inv);
    px[0] = make_float4(mm[0], mm[1], mm[2], mm[3]);
    px[1] = make_float4(mm[4], mm[5], mm[6], mm[7]);
}

// K3: 7x7 conv over [mean,max] -> sigmoid. grid=(256,16), 256 thr (one row).
__global__ void sa_conv(const float* __restrict__ spm, const float* __restrict__ spx,
                        const float* __restrict__ sw, float* __restrict__ sa) {
    int b = blockIdx.y, y = blockIdx.x, x = threadIdx.x;
    const float* in0 = spm + (size_t)b * HW_;
    const float* in1 = spx + (size_t)b * HW_;
    float acc = 0.f;
#pragma unroll
    for (int ky = 0; ky < 7; ++ky) {
        int yy = y + ky - 3;
        if (yy < 0 || yy >= H_) continue;
        const float* r0 = in0 + yy * W_;
        const float* r1 = in1 + yy * W_;
#pragma unroll
        for (int kx = 0; kx < 7; ++kx) {
            int xx = x + kx - 3;
            if (xx < 0 || xx >= W_) continue;
            acc += r0[xx] * sw[ky * 7 + kx] + r1[xx] * sw[49 + ky * 7 + kx];
        }
    }
    sa[(size_t)b * HW_ + y * W_ + x] = 1.f / (1.f + expf(-acc));
}

// K4: sval[b,c] = mean_hw(sa * weight) from fp8 weight. grid=1024 (XCD-chunked),
// 512 thr.
__global__ __launch_bounds__(512) void weighted_reduce(const u2v* __restrict__ wq,
                                const float* __restrict__ sa,
                                float* __restrict__ sval) {
    int d = blockIdx.x;
    int bc = ((d & 7) << 7) + (d >> 3);   // XCD-chunked: each XCD owns 2 images
    int b = bc >> 6;
    const u2v* wp = wq + (size_t)bc * (HW_ / 8);
    const float4* sp = (const float4*)(sa + (size_t)b * HW_);
    float s = 0.f;
#pragma unroll 4
    for (int i = threadIdx.x; i < HW_ / 8; i += 512) {
        u2v u = wp[i];
        float4 q0 = sp[2 * i], q1 = sp[2 * i + 1];
        f2v p01 = __builtin_amdgcn_cvt_pk_f32_fp8(u.x, false);
        f2v p23 = __builtin_amdgcn_cvt_pk_f32_fp8(u.x, true);
        f2v p45 = __builtin_amdgcn_cvt_pk_f32_fp8(u.y, false);
        f2v p67 = __builtin_amdgcn_cvt_pk_f32_fp8(u.y, true);
        s += p01.x * q0.x + p01.y * q0.y + p23.x * q0.z + p23.y * q0.w
           + p45.x * q1.x + p45.y * q1.y + p67.x * q1.z + p67.y * q1.w;
    }
    __shared__ float ts[8];
    int wid = threadIdx.x >> 6, lane = threadIdx.x & 63;
    s = waveSum(s);
    if (lane == 0) ts[wid] = s;
    __syncthreads();
    if (threadIdx.x == 0) {
        float a = 0.f;
#pragma unroll
        for (int j = 0; j < 8; ++j) a += ts[j];
        sval[bc] = a * (1.f / (float)HW_);
    }
}

// K5: build per-sample kernel (redundant per block) + dynamic 3x3x64 conv.
// grid=1024 (16 b x 64 tiles of 4 rows, XCD-chunked), 256 thr. (round-4 form)
__global__ __launch_bounds__(256) void final_conv(const float* __restrict__ x1,
                           const float* __restrict__ ca, const float* __restrict__ sval,
                           const float* __restrict__ pk1w, const float* __restrict__ pk1b,
                           const float* __restrict__ pk2w, const float* __restrict__ pk2b,
                           float* __restrict__ out) {
    int d = blockIdx.x;
    int gid = ((d & 7) << 7) + (d >> 3);  // XCD-chunked: each XCD owns 2 images
    int b = gid >> 6;
    int y0 = (gid & 63) * 4;
    int t = threadIdx.x;
    __shared__ float wg[64];
    __shared__ float kern[64][9];
    if (t < 64) wg[t] = ca[b * 64 + t] * sval[b * 64 + t];
    __syncthreads();
    if (t < 64) {
        float p = pk1b[t];
#pragma unroll 8
        for (int c = 0; c < 64; ++c) p += pk1w[t * 64 + c] * wg[c];
#pragma unroll
        for (int j = 0; j < 9; ++j) kern[t][j] = p * pk2w[t * 9 + j] + pk2b[t * 9 + j];
    }
    __syncthreads();

    int x = t;
    float acc[4] = {0.f, 0.f, 0.f, 0.f};

    for (int ic = 0; ic < 64; ++ic) {
        const float* plane = x1 + ((size_t)(b * 64 + ic) << 16);
        float k0 = kern[ic][0], k1 = kern[ic][1], k2 = kern[ic][2];
        float k3 = kern[ic][3], k4 = kern[ic][4], k5 = kern[ic][5];
        float k6 = kern[ic][6], k7 = kern[ic][7], k8 = kern[ic][8];
#pragma unroll
        for (int j = -1; j <= 4; ++j) {
            int yy = y0 + j;
            float m = 0.f, z = 0.f, p = 0.f;
            if (yy >= 0 && yy < H_) {
                const float* row = plane + yy * W_;
                z = row[x];
                m = (x > 0) ? row[x - 1] : 0.f;
                p = (x < W_ - 1) ? row[x + 1] : 0.f;
            }
            if (j <= 2) acc[j + 1] += m * k0 + z * k1 + p * k2;
            if (j >= 0 && j <= 3) acc[j] += m * k3 + z * k4 + p * k5;
            if (j >= 1) acc[j - 1] += m * k6 + z * k7 + p * k8;
        }
    }
#pragma unroll
    for (int r = 0; r < 4; ++r)
        out[(size_t)b * HW_ + (size_t)(y0 + r) * W_ + x] = acc[r];
}

extern "C" void kernel_launch(void* const* d_in, const int* in_sizes, int n_in,
                              void* d_out, int out_size, void* d_ws, size_t ws_size,
                              hipStream_t stream) {
    const float* x1     = (const float*)d_in[0];
    const float* weight = (const float*)d_in[1];
    const float* fc1    = (const float*)d_in[2];
    const float* fc2    = (const float*)d_in[3];
    const float* saw    = (const float*)d_in[4];
    const float* pk1w   = (const float*)d_in[5];
    const float* pk1b   = (const float*)d_in[6];
    const float* pk2w   = (const float*)d_in[7];
    const float* pk2b   = (const float*)d_in[8];
    float* out = (float*)d_out;

    float* ws   = (float*)d_ws;
    float* wsum = ws;                         // 1024
    float* wmax = ws + 1024;                  // 1024
    float* ca   = ws + 2048;                  // 1024
    float* sval = ws + 3072;                  // 1024
    float* spm  = ws + 16384;                 // 1048576
    float* spx  = spm + (size_t)B_ * HW_;     // 1048576
    float* sa   = spx + (size_t)B_ * HW_;     // 1048576
    u2v*   wq   = (u2v*)(ws + 16384 + 3u * 1048576u);  // 67 MB fp8

    reduce_weight_q<<<dim3(B_ * C_), 512, 0, stream>>>(weight, wq, wsum, wmax);
    ca_spatial<<<dim3(32, B_), 256, 0, stream>>>(wq, wsum, wmax, fc1, fc2, spm, spx, ca);
    sa_conv<<<dim3(H_, B_), 256, 0, stream>>>(spm, spx, saw, sa);
    weighted_reduce<<<dim3(B_ * C_), 512, 0, stream>>>(wq, sa, sval);
    final_conv<<<dim3(B_ * C_), 256, 0, stream>>>(x1, ca, sval, pk1w, pk1b, pk2w, pk2b, out);
}